// Round 2
// baseline (199.540 us; speedup 1.0000x reference)
//
#include <hip/hip_runtime.h>
#include <hip/hip_bf16.h>

#define L 401
#define D 128
#define BATCH 2

typedef __attribute__((ext_vector_type(8))) short short8;
typedef __attribute__((ext_vector_type(4))) float f32x4;

__device__ __forceinline__ ushort bf16_bits(float f) {
  __hip_bfloat16 h = __float2bfloat16(f);
  return *reinterpret_cast<ushort*>(&h);
}

// read a 16B A/B fragment from a swizzled 128x128 bf16 LDS tile
__device__ __forceinline__ short8 frag_read(const char* lds, int row, int cb) {
  return *(const short8*)(lds + row * 256 + (cb ^ ((row & 7) << 4)));
}

// stage a 128x128 bf16 tile (src row stride = 128 elems) into LDS with
// XOR-swizzled writes. Source rows are row0+r clamped to rowmax.
__device__ __forceinline__ void stage128x128(char* lds, const __hip_bfloat16* src,
                                             int row0, int rowmax, int tid) {
#pragma unroll
  for (int it = 0; it < 8; ++it) {
    int r = it * 16 + (tid >> 4);
    int cb = (tid & 15) * 16;
    int sr = row0 + r;
    sr = sr > rowmax ? rowmax : sr;
    short8 v = *(const short8*)((const char*)src + (size_t)sr * (D * 2) + cb);
    *(short8*)(lds + r * 256 + (cb ^ ((r & 7) << 4))) = v;
  }
}

// ---------------- kernel 1: casts ----------------
__global__ void cast_kernel(const float* __restrict__ x, const float* __restrict__ w1,
                            __hip_bfloat16* __restrict__ xbf, __hip_bfloat16* __restrict__ w1bf) {
  int idx = blockIdx.x * 256 + threadIdx.x;
  const int n1 = BATCH * L * D;
  if (idx < n1) {
    xbf[idx] = __float2bfloat16(x[idx]);
  } else {
    int j = idx - n1;
    if (j < D * D) w1bf[j] = __float2bfloat16(w1[j]);
  }
}

// ---------------- kernel 2: W_bil[k][d][e] -> Wbt[k][e][d] (bf16) ----------------
__global__ void transpose_wbil(const float* __restrict__ Wb, __hip_bfloat16* __restrict__ wbt) {
  int k = blockIdx.x;
  const float* in = Wb + (size_t)k * D * D;
  __hip_bfloat16* out = wbt + (size_t)k * D * D;
  for (int n = threadIdx.x; n < (D / 4) * D; n += 256) {
    int d0 = (n >> 7) * 4;
    int e = n & 127;
    ushort4 o;
    o.x = bf16_bits(in[(d0 + 0) * D + e]);
    o.y = bf16_bits(in[(d0 + 1) * D + e]);
    o.z = bf16_bits(in[(d0 + 2) * D + e]);
    o.w = bf16_bits(in[(d0 + 3) * D + e]);
    *(ushort4*)((ushort*)out + e * D + d0) = o;
  }
}

// ---------------- kernel 3: tmp[b,i,k,e] = sum_d x[b,i,d] * Wbt[k,e,d] ----------------
__global__ __launch_bounds__(256, 2) void gemm_tmp(const __hip_bfloat16* __restrict__ xbf,
                                                   const __hip_bfloat16* __restrict__ wbt,
                                                   __hip_bfloat16* __restrict__ tmp) {
  __shared__ char ldsA[128 * 256];
  __shared__ char ldsB[128 * 256];
  const int tid = threadIdx.x;
  const int lane = tid & 63;
  const int w = tid >> 6;
  const int c0 = lane & 15;
  const int lg = lane >> 4;
  const int kt = blockIdx.x;       // which k (n-slab of 128 = one full k slice)
  const int i0 = blockIdx.y * 128; // M tile
  const int b = blockIdx.z;

  stage128x128(ldsA, xbf + (size_t)b * L * D, i0, L - 1, tid);
  stage128x128(ldsB, wbt + (size_t)kt * D * D, 0, 127, tid);
  __syncthreads();

  f32x4 acc[2][8];
#pragma unroll
  for (int rf = 0; rf < 2; ++rf)
#pragma unroll
    for (int cf = 0; cf < 8; ++cf) acc[rf][cf] = (f32x4){0.f, 0.f, 0.f, 0.f};

#pragma unroll
  for (int ks = 0; ks < 4; ++ks) {
    const int cb = ks * 64 + lg * 16;
    short8 a0 = frag_read(ldsA, w * 32 + c0, cb);
    short8 a1 = frag_read(ldsA, w * 32 + 16 + c0, cb);
#pragma unroll
    for (int cf = 0; cf < 8; ++cf) {
      short8 bb = frag_read(ldsB, cf * 16 + c0, cb);
      acc[0][cf] = __builtin_amdgcn_mfma_f32_16x16x32_bf16(a0, bb, acc[0][cf], 0, 0, 0);
      acc[1][cf] = __builtin_amdgcn_mfma_f32_16x16x32_bf16(a1, bb, acc[1][cf], 0, 0, 0);
    }
  }

  ushort* out = (ushort*)tmp;
#pragma unroll
  for (int rf = 0; rf < 2; ++rf)
#pragma unroll
    for (int cf = 0; cf < 8; ++cf)
#pragma unroll
      for (int r = 0; r < 4; ++r) {
        int i = i0 + w * 32 + rf * 16 + lg * 4 + r;
        if (i < L) {
          int col = cf * 16 + c0;
          out[((size_t)(b * L + i)) * (D * D) + kt * D + col] = bf16_bits(acc[rf][cf][r]);
        }
      }
}

// ---------------- kernel 4: fused pair -> LN -> Linear+GELU -> dot(w2) ----------------
__global__ __launch_bounds__(256, 2) void fused_contact(
    const __hip_bfloat16* __restrict__ xbf, const __hip_bfloat16* __restrict__ tmp,
    const __hip_bfloat16* __restrict__ w1bf, const float* __restrict__ b_bil,
    const float* __restrict__ ln_g, const float* __restrict__ ln_b,
    const float* __restrict__ b1, const float* __restrict__ w2,
    const float* __restrict__ b2, float* __restrict__ cont) {
  __shared__ char ldsX[128 * 256];
  __shared__ char ldsT[128 * 256];
  const int tid = threadIdx.x;
  const int lane = tid & 63;
  const int w = tid >> 6;
  const int c0 = lane & 15;
  const int lg = lane >> 4;
  const int b = blockIdx.z;
  const int i = blockIdx.y;
  const int j0 = blockIdx.x * 128;

  stage128x128(ldsX, xbf + (size_t)b * L * D, j0, L - 1, tid);
  stage128x128(ldsT, tmp + ((size_t)(b * L + i)) * (D * D), 0, 127, tid);
  __syncthreads();

  // GEMM1: pair[j][k] = sum_e Xj[j][e] * tmp_i[k][e]  (A = Xj rows, B^T = tmp_i rows)
  f32x4 acc[2][8];
#pragma unroll
  for (int rf = 0; rf < 2; ++rf)
#pragma unroll
    for (int cf = 0; cf < 8; ++cf) acc[rf][cf] = (f32x4){0.f, 0.f, 0.f, 0.f};

#pragma unroll
  for (int ks = 0; ks < 4; ++ks) {
    const int cb = ks * 64 + lg * 16;
    short8 a0 = frag_read(ldsX, w * 32 + c0, cb);
    short8 a1 = frag_read(ldsX, w * 32 + 16 + c0, cb);
#pragma unroll
    for (int cf = 0; cf < 8; ++cf) {
      short8 bb = frag_read(ldsT, cf * 16 + c0, cb);
      acc[0][cf] = __builtin_amdgcn_mfma_f32_16x16x32_bf16(a0, bb, acc[0][cf], 0, 0, 0);
      acc[1][cf] = __builtin_amdgcn_mfma_f32_16x16x32_bf16(a1, bb, acc[1][cf], 0, 0, 0);
    }
  }

  // bias + LayerNorm over k (row-wise; row r lives in one 16-lane group)
  float lngv[8], lnbv[8];
#pragma unroll
  for (int cf = 0; cf < 8; ++cf) {
    const int c = cf * 16 + c0;
    const float bbia = b_bil[c];
#pragma unroll
    for (int rf = 0; rf < 2; ++rf)
#pragma unroll
      for (int r = 0; r < 4; ++r) acc[rf][cf][r] += bbia;
    lngv[cf] = ln_g[c];
    lnbv[cf] = ln_b[c];
  }
  float mu[2][4], rs[2][4];
#pragma unroll
  for (int rf = 0; rf < 2; ++rf)
#pragma unroll
    for (int r = 0; r < 4; ++r) {
      float s = 0.f, q = 0.f;
#pragma unroll
      for (int cf = 0; cf < 8; ++cf) {
        float v = acc[rf][cf][r];
        s += v;
        q += v * v;
      }
      s += __shfl_xor(s, 1); s += __shfl_xor(s, 2); s += __shfl_xor(s, 4); s += __shfl_xor(s, 8);
      q += __shfl_xor(q, 1); q += __shfl_xor(q, 2); q += __shfl_xor(q, 4); q += __shfl_xor(q, 8);
      const float m = s * (1.f / 128.f);
      float var = q * (1.f / 128.f) - m * m;
      mu[rf][r] = m;
      rs[rf][r] = rsqrtf(var + 1e-5f);
    }

  __syncthreads(); // all waves done reading ldsX/ldsT for GEMM1

  // write normalized bf16 tile into ldsX (same swizzle), stage W1 into ldsT
#pragma unroll
  for (int rf = 0; rf < 2; ++rf)
#pragma unroll
    for (int cf = 0; cf < 8; ++cf)
#pragma unroll
      for (int r = 0; r < 4; ++r) {
        const int row = w * 32 + rf * 16 + lg * 4 + r;
        const int colb = (cf * 16 + c0) * 2;
        const float v = (acc[rf][cf][r] - mu[rf][r]) * rs[rf][r] * lngv[cf] + lnbv[cf];
        *(ushort*)(ldsX + row * 256 + (colb ^ ((row & 7) << 4))) = bf16_bits(v);
      }
  stage128x128(ldsT, w1bf, 0, 127, tid);
  __syncthreads();

  // GEMM2: h[j][e] = sum_d N[j][d] * W1[e][d]
  f32x4 acc2[2][8];
#pragma unroll
  for (int rf = 0; rf < 2; ++rf)
#pragma unroll
    for (int cf = 0; cf < 8; ++cf) acc2[rf][cf] = (f32x4){0.f, 0.f, 0.f, 0.f};

#pragma unroll
  for (int ks = 0; ks < 4; ++ks) {
    const int cb = ks * 64 + lg * 16;
    short8 a0 = frag_read(ldsX, w * 32 + c0, cb);
    short8 a1 = frag_read(ldsX, w * 32 + 16 + c0, cb);
#pragma unroll
    for (int cf = 0; cf < 8; ++cf) {
      short8 bb = frag_read(ldsT, cf * 16 + c0, cb);
      acc2[0][cf] = __builtin_amdgcn_mfma_f32_16x16x32_bf16(a0, bb, acc2[0][cf], 0, 0, 0);
      acc2[1][cf] = __builtin_amdgcn_mfma_f32_16x16x32_bf16(a1, bb, acc2[1][cf], 0, 0, 0);
    }
  }

  // epilogue: +b1, exact GELU, dot with w2, row-reduce, store contact
  float b1v[8], w2v[8];
#pragma unroll
  for (int cf = 0; cf < 8; ++cf) {
    const int c = cf * 16 + c0;
    b1v[cf] = b1[c];
    w2v[cf] = w2[c];
  }
  const float b2v = b2[0];
  float part[2][4];
#pragma unroll
  for (int rf = 0; rf < 2; ++rf)
#pragma unroll
    for (int r = 0; r < 4; ++r) part[rf][r] = 0.f;
#pragma unroll
  for (int rf = 0; rf < 2; ++rf)
#pragma unroll
    for (int cf = 0; cf < 8; ++cf)
#pragma unroll
      for (int r = 0; r < 4; ++r) {
        const float v = acc2[rf][cf][r] + b1v[cf];
        const float g = 0.5f * v * (1.f + erff(v * 0.70710678118654752f));
        part[rf][r] += g * w2v[cf];
      }
#pragma unroll
  for (int rf = 0; rf < 2; ++rf)
#pragma unroll
    for (int r = 0; r < 4; ++r) {
      float p = part[rf][r];
      p += __shfl_xor(p, 1); p += __shfl_xor(p, 2); p += __shfl_xor(p, 4); p += __shfl_xor(p, 8);
      if (c0 == 0) {
        const int j = j0 + w * 32 + rf * 16 + lg * 4 + r;
        if (j < L) cont[((size_t)(b * L + i)) * L + j] = p + b2v;
      }
    }
}

// ---------------- kernel 5: symmetrize ----------------
__global__ void sym_kernel(const float* __restrict__ c, float* __restrict__ out) {
  int idx = blockIdx.x * 256 + threadIdx.x;
  const int n = BATCH * L * L;
  if (idx >= n) return;
  int b = idx / (L * L);
  int r = idx - b * (L * L);
  int i = r / L;
  int j = r - i * L;
  out[idx] = 0.5f * (c[(size_t)b * L * L + (size_t)i * L + j] +
                     c[(size_t)b * L * L + (size_t)j * L + i]);
}

extern "C" void kernel_launch(void* const* d_in, const int* in_sizes, int n_in,
                              void* d_out, int out_size, void* d_ws, size_t ws_size,
                              hipStream_t stream) {
  const float* x     = (const float*)d_in[0];
  const float* W_bil = (const float*)d_in[1];
  const float* b_bil = (const float*)d_in[2];
  const float* ln_g  = (const float*)d_in[3];
  const float* ln_b  = (const float*)d_in[4];
  const float* W1    = (const float*)d_in[5];
  const float* b1    = (const float*)d_in[6];
  const float* w2    = (const float*)d_in[7];
  const float* b2    = (const float*)d_in[8];
  float* out = (float*)d_out;

  char* ws = (char*)d_ws;
  // ws layout (all offsets 256B-aligned):
  __hip_bfloat16* xbf  = (__hip_bfloat16*)(ws + 0);        // 2*401*128*2   = 205,312 B
  __hip_bfloat16* w1bf = (__hip_bfloat16*)(ws + 205312);   // 128*128*2     =  32,768 B
  __hip_bfloat16* wbt  = (__hip_bfloat16*)(ws + 238080);   // 128^3*2       = 4,194,304 B
  __hip_bfloat16* tmp  = (__hip_bfloat16*)(ws + 4432384);  // 2*401*128*128*2 = 26,279,936 B
  float* cont          = (float*)(ws + 30712320);          // 2*401*401*4   = 1,286,408 B

  const int ncast = BATCH * L * D + D * D;
  cast_kernel<<<(ncast + 255) / 256, 256, 0, stream>>>(x, W1, xbf, w1bf);
  transpose_wbil<<<D, 256, 0, stream>>>(W_bil, wbt);
  gemm_tmp<<<dim3(D, 4, BATCH), 256, 0, stream>>>(xbf, wbt, tmp);
  fused_contact<<<dim3(4, L, BATCH), 256, 0, stream>>>(xbf, tmp, w1bf, b_bil, ln_g, ln_b,
                                                       b1, w2, b2, cont);
  sym_kernel<<<(BATCH * L * L + 255) / 256, 256, 0, stream>>>(cont, out);
}

// Round 3
// 169.280 us; speedup vs baseline: 1.1788x; 1.1788x over previous
//
#include <hip/hip_runtime.h>
#include <hip/hip_bf16.h>

#define L 401
#define D 128
#define BATCH 2

typedef __attribute__((ext_vector_type(8))) short short8;
typedef __attribute__((ext_vector_type(4))) float f32x4;

__device__ __forceinline__ ushort bf16_bits(float f) {
  __hip_bfloat16 h = __float2bfloat16(f);
  return *reinterpret_cast<ushort*>(&h);
}

// read a 16B A/B fragment from a swizzled 128x128 bf16 LDS tile
__device__ __forceinline__ short8 frag_read(const char* lds, int row, int cb) {
  return *(const short8*)(lds + row * 256 + (cb ^ ((row & 7) << 4)));
}

// stage a 128x128 bf16 tile (src row stride = 128 elems) into LDS with
// XOR-swizzled writes; 512-thread version. Source rows row0+r clamped.
__device__ __forceinline__ void stage128x128_512(char* lds, const __hip_bfloat16* src,
                                                 int row0, int rowmax, int tid) {
#pragma unroll
  for (int it = 0; it < 4; ++it) {
    int r = it * 32 + (tid >> 4);
    int cb = (tid & 15) * 16;
    int sr = row0 + r;
    sr = sr > rowmax ? rowmax : sr;
    short8 v = *(const short8*)((const char*)src + (size_t)sr * (D * 2) + cb);
    *(short8*)(lds + r * 256 + (cb ^ ((r & 7) << 4))) = v;
  }
}

// branch-free erf-based GELU epilogue term: g(v) = v * Phi(v)
// Phi via A&S 7.1.26 erf (|err| <= 1.5e-7), coefficients pre-halved.
__device__ __forceinline__ float gelu_fast(float v) {
  const float a = fabsf(v) * 0.70710678118654752f;  // |v|/sqrt(2)
  const float t = __builtin_amdgcn_rcpf(fmaf(a, 0.3275911f, 1.0f));
  float p = fmaf(t, 0.530702714f, -0.726576013f);
  p = fmaf(p, t, 0.710706870f);
  p = fmaf(p, t, -0.142248368f);
  p = fmaf(p, t, 0.127414796f);
  p = p * t;                                         // 0.5*(A&S poly)
  const float e = __builtin_amdgcn_exp2f(a * a * -1.4426950408889634f);
  const float q = p * e;                             // 0.5*(1 - erf(a))
  const float cdf = (v < 0.f) ? q : 1.0f - q;
  return v * cdf;
}

// ---------------- kernel 1: casts ----------------
__global__ void cast_kernel(const float* __restrict__ x, const float* __restrict__ w1,
                            __hip_bfloat16* __restrict__ xbf, __hip_bfloat16* __restrict__ w1bf) {
  int idx = blockIdx.x * 256 + threadIdx.x;
  const int n1 = BATCH * L * D;
  if (idx < n1) {
    xbf[idx] = __float2bfloat16(x[idx]);
  } else {
    int j = idx - n1;
    if (j < D * D) w1bf[j] = __float2bfloat16(w1[j]);
  }
}

// ---------------- kernel 2: W_bil[k][d][e] -> Wbt[k][e][d] (bf16), LDS transpose ----------------
__global__ void transpose_wbil(const float* __restrict__ Wb, __hip_bfloat16* __restrict__ wbt) {
  __shared__ alignas(16) ushort t[128 * 136];  // pad 136 to vary banks / keep 8B align
  const int tid = threadIdx.x;
  const int k = blockIdx.x;
  const float* in = Wb + (size_t)k * D * D;
  // coalesced float4 reads, transposed scalar LDS writes
#pragma unroll
  for (int it = 0; it < 16; ++it) {
    int idx = it * 256 + tid;        // float4 index; 4096 total
    int d = idx >> 5;                // 32 float4 per row
    int e = (idx & 31) * 4;
    float4 f4 = ((const float4*)in)[idx];
    t[(e + 0) * 136 + d] = bf16_bits(f4.x);
    t[(e + 1) * 136 + d] = bf16_bits(f4.y);
    t[(e + 2) * 136 + d] = bf16_bits(f4.z);
    t[(e + 3) * 136 + d] = bf16_bits(f4.w);
  }
  __syncthreads();
  // coalesced 8B writes: thread -> (e = tid/2, 64-wide d half)
  ushort* out = (ushort*)(wbt + (size_t)k * D * D);
  const int e = tid >> 1;
  const int d0 = (tid & 1) * 64;
#pragma unroll
  for (int c = 0; c < 16; ++c) {
    *(ushort4*)&out[e * D + d0 + c * 4] = *(ushort4*)&t[e * 136 + d0 + c * 4];
  }
}

// ---------------- kernel 3: tmp[b,i,k,e] = sum_d x[b,i,d] * Wbt[k,e,d] ----------------
// Roles: A = Wbt[kt] rows e, B = x rows i  ->  C[row=e, col=i]; in-lane 4
// consecutive e -> packed 8B stores.
__global__ __launch_bounds__(512, 4) void gemm_tmp(const __hip_bfloat16* __restrict__ xbf,
                                                   const __hip_bfloat16* __restrict__ wbt,
                                                   __hip_bfloat16* __restrict__ tmp) {
  __shared__ char ldsE[128 * 256];
  __shared__ char ldsI[128 * 256];
  const int tid = threadIdx.x;
  const int lane = tid & 63;
  const int w = tid >> 6;     // 0..7
  const int c0 = lane & 15;
  const int lg = lane >> 4;
  const int kt = blockIdx.x;
  const int i0 = blockIdx.y * 128;
  const int b = blockIdx.z;

  stage128x128_512(ldsI, xbf + (size_t)b * L * D, i0, L - 1, tid);
  stage128x128_512(ldsE, wbt + (size_t)kt * D * D, 0, 127, tid);
  __syncthreads();

  f32x4 acc[8];
#pragma unroll
  for (int cf = 0; cf < 8; ++cf) acc[cf] = (f32x4){0.f, 0.f, 0.f, 0.f};

#pragma unroll
  for (int ks = 0; ks < 4; ++ks) {
    const int cb = ks * 64 + lg * 16;
    short8 ae = frag_read(ldsE, w * 16 + c0, cb);
#pragma unroll
    for (int cf = 0; cf < 8; ++cf) {
      short8 bi = frag_read(ldsI, cf * 16 + c0, cb);
      acc[cf] = __builtin_amdgcn_mfma_f32_16x16x32_bf16(ae, bi, acc[cf], 0, 0, 0);
    }
  }

  ushort* outp = (ushort*)tmp;
  const int e0 = w * 16 + lg * 4;
#pragma unroll
  for (int cf = 0; cf < 8; ++cf) {
    const int i = i0 + cf * 16 + c0;
    if (i < L) {
      uint lo = (uint)bf16_bits(acc[cf][0]) | ((uint)bf16_bits(acc[cf][1]) << 16);
      uint hi = (uint)bf16_bits(acc[cf][2]) | ((uint)bf16_bits(acc[cf][3]) << 16);
      uint2 v; v.x = lo; v.y = hi;
      *(uint2*)(outp + ((size_t)(b * L + i)) * (D * D) + kt * D + e0) = v;
    }
  }
}

// ---------------- kernel 4: fused pair -> LN -> Linear+GELU -> dot(w2) ----------------
// 8 waves; wave w owns 16 j-rows (w*16..w*16+15) x all 128 cols.
__global__ __launch_bounds__(512, 4) void fused_contact(
    const __hip_bfloat16* __restrict__ xbf, const __hip_bfloat16* __restrict__ tmp,
    const __hip_bfloat16* __restrict__ w1bf, const float* __restrict__ b_bil,
    const float* __restrict__ ln_g, const float* __restrict__ ln_b,
    const float* __restrict__ b1, const float* __restrict__ w2,
    const float* __restrict__ b2, float* __restrict__ cont) {
  __shared__ char ldsX[128 * 256];
  __shared__ char ldsT[128 * 256];
  const int tid = threadIdx.x;
  const int lane = tid & 63;
  const int w = tid >> 6;     // 0..7
  const int c0 = lane & 15;
  const int lg = lane >> 4;
  const int b = blockIdx.z;
  const int i = blockIdx.y;
  const int j0 = blockIdx.x * 128;

  stage128x128_512(ldsX, xbf + (size_t)b * L * D, j0, L - 1, tid);
  stage128x128_512(ldsT, tmp + ((size_t)(b * L + i)) * (D * D), 0, 127, tid);
  __syncthreads();

  // GEMM1: pair[j][k] = sum_e Xj[j][e] * tmp_i[k][e]
  f32x4 acc[8];
#pragma unroll
  for (int cf = 0; cf < 8; ++cf) acc[cf] = (f32x4){0.f, 0.f, 0.f, 0.f};

#pragma unroll
  for (int ks = 0; ks < 4; ++ks) {
    const int cb = ks * 64 + lg * 16;
    short8 a0 = frag_read(ldsX, w * 16 + c0, cb);
#pragma unroll
    for (int cf = 0; cf < 8; ++cf) {
      short8 bb = frag_read(ldsT, cf * 16 + c0, cb);
      acc[cf] = __builtin_amdgcn_mfma_f32_16x16x32_bf16(a0, bb, acc[cf], 0, 0, 0);
    }
  }

  // bias + LayerNorm over k (row r lives in one 16-lane group)
  float lngv[8], lnbv[8];
#pragma unroll
  for (int cf = 0; cf < 8; ++cf) {
    const int c = cf * 16 + c0;
    const float bbia = b_bil[c];
#pragma unroll
    for (int r = 0; r < 4; ++r) acc[cf][r] += bbia;
    lngv[cf] = ln_g[c];
    lnbv[cf] = ln_b[c];
  }
  float mu[4], rs[4];
#pragma unroll
  for (int r = 0; r < 4; ++r) {
    float s = 0.f, q = 0.f;
#pragma unroll
    for (int cf = 0; cf < 8; ++cf) {
      float v = acc[cf][r];
      s += v;
      q += v * v;
    }
    s += __shfl_xor(s, 1); s += __shfl_xor(s, 2); s += __shfl_xor(s, 4); s += __shfl_xor(s, 8);
    q += __shfl_xor(q, 1); q += __shfl_xor(q, 2); q += __shfl_xor(q, 4); q += __shfl_xor(q, 8);
    const float m = s * (1.f / 128.f);
    float var = q * (1.f / 128.f) - m * m;
    mu[r] = m;
    rs[r] = __builtin_amdgcn_rsqf(var + 1e-5f);
  }

  __syncthreads(); // all waves done reading ldsX/ldsT for GEMM1

  // write normalized bf16 tile into ldsX (same swizzle), stage W1 into ldsT
#pragma unroll
  for (int cf = 0; cf < 8; ++cf)
#pragma unroll
    for (int r = 0; r < 4; ++r) {
      const int row = w * 16 + lg * 4 + r;
      const int colb = (cf * 16 + c0) * 2;
      const float v = (acc[cf][r] - mu[r]) * rs[r] * lngv[cf] + lnbv[cf];
      *(ushort*)(ldsX + row * 256 + (colb ^ ((row & 7) << 4))) = bf16_bits(v);
    }
  stage128x128_512(ldsT, w1bf, 0, 127, tid);
  __syncthreads();

  // GEMM2: h[j][e] = sum_d N[j][d] * W1[e][d]
  f32x4 acc2[8];
#pragma unroll
  for (int cf = 0; cf < 8; ++cf) acc2[cf] = (f32x4){0.f, 0.f, 0.f, 0.f};

#pragma unroll
  for (int ks = 0; ks < 4; ++ks) {
    const int cb = ks * 64 + lg * 16;
    short8 a0 = frag_read(ldsX, w * 16 + c0, cb);
#pragma unroll
    for (int cf = 0; cf < 8; ++cf) {
      short8 bb = frag_read(ldsT, cf * 16 + c0, cb);
      acc2[cf] = __builtin_amdgcn_mfma_f32_16x16x32_bf16(a0, bb, acc2[cf], 0, 0, 0);
    }
  }

  // epilogue: +b1, fast exact GELU, dot with w2, row-reduce, store contact
  float b1v[8], w2v[8];
#pragma unroll
  for (int cf = 0; cf < 8; ++cf) {
    const int c = cf * 16 + c0;
    b1v[cf] = b1[c];
    w2v[cf] = w2[c];
  }
  const float b2v = b2[0];
  float part[4] = {0.f, 0.f, 0.f, 0.f};
#pragma unroll
  for (int cf = 0; cf < 8; ++cf)
#pragma unroll
    for (int r = 0; r < 4; ++r) {
      const float v = acc2[cf][r] + b1v[cf];
      part[r] += gelu_fast(v) * w2v[cf];
    }
#pragma unroll
  for (int r = 0; r < 4; ++r) {
    float p = part[r];
    p += __shfl_xor(p, 1); p += __shfl_xor(p, 2); p += __shfl_xor(p, 4); p += __shfl_xor(p, 8);
    if (c0 == 0) {
      const int j = j0 + w * 16 + lg * 4 + r;
      if (j < L) cont[((size_t)(b * L + i)) * L + j] = p + b2v;
    }
  }
}

// ---------------- kernel 5: symmetrize ----------------
__global__ void sym_kernel(const float* __restrict__ c, float* __restrict__ out) {
  int idx = blockIdx.x * 256 + threadIdx.x;
  const int n = BATCH * L * L;
  if (idx >= n) return;
  int b = idx / (L * L);
  int r = idx - b * (L * L);
  int i = r / L;
  int j = r - i * L;
  out[idx] = 0.5f * (c[(size_t)b * L * L + (size_t)i * L + j] +
                     c[(size_t)b * L * L + (size_t)j * L + i]);
}

extern "C" void kernel_launch(void* const* d_in, const int* in_sizes, int n_in,
                              void* d_out, int out_size, void* d_ws, size_t ws_size,
                              hipStream_t stream) {
  const float* x     = (const float*)d_in[0];
  const float* W_bil = (const float*)d_in[1];
  const float* b_bil = (const float*)d_in[2];
  const float* ln_g  = (const float*)d_in[3];
  const float* ln_b  = (const float*)d_in[4];
  const float* W1    = (const float*)d_in[5];
  const float* b1    = (const float*)d_in[6];
  const float* w2    = (const float*)d_in[7];
  const float* b2    = (const float*)d_in[8];
  float* out = (float*)d_out;

  char* ws = (char*)d_ws;
  __hip_bfloat16* xbf  = (__hip_bfloat16*)(ws + 0);        // 205,312 B
  __hip_bfloat16* w1bf = (__hip_bfloat16*)(ws + 205312);   // 32,768 B
  __hip_bfloat16* wbt  = (__hip_bfloat16*)(ws + 238080);   // 4,194,304 B
  __hip_bfloat16* tmp  = (__hip_bfloat16*)(ws + 4432384);  // 26,279,936 B
  float* cont          = (float*)(ws + 30712320);          // 1,286,408 B

  const int ncast = BATCH * L * D + D * D;
  cast_kernel<<<(ncast + 255) / 256, 256, 0, stream>>>(x, W1, xbf, w1bf);
  transpose_wbil<<<D, 256, 0, stream>>>(W_bil, wbt);
  gemm_tmp<<<dim3(D, 4, BATCH), 512, 0, stream>>>(xbf, wbt, tmp);
  fused_contact<<<dim3(4, L, BATCH), 512, 0, stream>>>(xbf, tmp, w1bf, b_bil, ln_g, ln_b,
                                                       b1, w2, b2, cont);
  sym_kernel<<<(BATCH * L * L + 255) / 256, 256, 0, stream>>>(cont, out);
}